// Round 1
// baseline (483.800 us; speedup 1.0000x reference)
//
#include <hip/hip_runtime.h>

// SelfAttentionNarrow: B=4, T=2048, EMB=1024, H=16, S=64.
// Pipeline: prep (W -> bf16, scale folded) -> qkv (MFMA GEMM) ->
//           flash attention (online softmax, P via LDS) -> out-proj GEMM + bias.
// All MFMA: v_mfma_f32_16x16x32_bf16, fp32 accumulate.
// Fragment layouts (gfx950, per guide §3):
//   A (16x32): row = lane&15, k = (lane>>4)*8 + e   (8 bf16 / lane)
//   B (32x16): col = lane&15, k = (lane>>4)*8 + e
//   C/D      : col = lane&15, row = (lane>>4)*4 + r (4 f32 / lane)

typedef float f32x4 __attribute__((ext_vector_type(4)));
typedef __bf16 bf16x8 __attribute__((ext_vector_type(8)));

#define MFMA16(a, b, c) __builtin_amdgcn_mfma_f32_16x16x32_bf16((a), (b), (c), 0, 0, 0)

constexpr int Tn = 2048;
constexpr int Hn = 16;
constexpr int Sn = 64;
constexpr int Bn = 4;
constexpr int EMBn = 1024;
constexpr float NEG_INF = -3.0e38f;

// ---------------------------------------------------------------- prep ----
// Convert weights to bf16. Fold softmax 1/sqrt(sqrt(EMB)) scale into Wk, Wq.
__global__ __launch_bounds__(256) void sa_prep(
    const float* __restrict__ Wk, const float* __restrict__ Wq,
    const float* __restrict__ Wv, const float* __restrict__ Wu,
    __bf16* __restrict__ w3, __bf16* __restrict__ wub) {
  int idx = blockIdx.x * 256 + threadIdx.x;
  const float rs = 0.17677669529663687f;  // 1024^-0.25
  if (idx < 1048576) wub[idx] = (__bf16)Wu[idx];
  if (idx < 4096) {
    w3[idx]        = (__bf16)(Wk[idx] * rs);
    w3[4096 + idx] = (__bf16)(Wq[idx] * rs);
    w3[8192 + idx] = (__bf16)(Wv[idx]);
  }
}

// ----------------------------------------------------------------- qkv ----
// GEMM: rows = (b,t,h) flat (131072), K = 64 (s), N = 192 (3 x 64 outputs).
// x is fp32; convert to bf16 fragments on the fly. Outputs in [n=b*16+h][t][s].
__global__ __launch_bounds__(256) void sa_qkv(
    const float* __restrict__ x, const __bf16* __restrict__ w3,
    __bf16* __restrict__ Qb, __bf16* __restrict__ Kb, __bf16* __restrict__ Vb) {
  const int wave = threadIdx.x >> 6;
  const int lane = threadIdx.x & 63;
  const int g = lane >> 4, c = lane & 15;
  const int row0 = blockIdx.x * 64 + wave * 16;  // 16 rows per wave

  // A fragments: x rows, fp32 -> bf16
  bf16x8 ax[2];
#pragma unroll
  for (int kk = 0; kk < 2; ++kk) {
    const float* xp = x + (long)(row0 + c) * 64 + kk * 32 + g * 8;
    f32x4 u = *(const f32x4*)xp;
    f32x4 v = *(const f32x4*)(xp + 4);
    bf16x8 a;
    a[0] = (__bf16)u[0]; a[1] = (__bf16)u[1]; a[2] = (__bf16)u[2]; a[3] = (__bf16)u[3];
    a[4] = (__bf16)v[0]; a[5] = (__bf16)v[1]; a[6] = (__bf16)v[2]; a[7] = (__bf16)v[3];
    ax[kk] = a;
  }

  f32x4 acc[3][4];
#pragma unroll
  for (int w = 0; w < 3; ++w)
#pragma unroll
    for (int ot = 0; ot < 4; ++ot) {
      f32x4 a_ = {0.f, 0.f, 0.f, 0.f};
#pragma unroll
      for (int kk = 0; kk < 2; ++kk) {
        bf16x8 b = *(const bf16x8*)(w3 + w * 4096 + (ot * 16 + c) * 64 + kk * 32 + g * 8);
        a_ = MFMA16(ax[kk], b, a_);
      }
      acc[w][ot] = a_;
    }

  __bf16* outs[3] = {Kb, Qb, Vb};  // input order: Wk, Wq, Wv
#pragma unroll
  for (int r = 0; r < 4; ++r) {
    int row = row0 + g * 4 + r;          // (b*T + t)*H + h
    int b = row >> 15;                   // / (T*H)
    int t = (row >> 4) & (Tn - 1);
    int h = row & 15;
    long ob = ((long)((b * 16 + h) * Tn + t)) * 64;
#pragma unroll
    for (int w = 0; w < 3; ++w)
#pragma unroll
      for (int ot = 0; ot < 4; ++ot)
        outs[w][ob + ot * 16 + c] = (__bf16)acc[w][ot][r];
  }
}

// --------------------------------------------------------------- flash ----
// grid (T/64, B*H). Block = 4 waves; wave owns 16 q rows. KV tile = 32.
__global__ __launch_bounds__(256) void sa_flash(
    const __bf16* __restrict__ Qb, const __bf16* __restrict__ Kb,
    const __bf16* __restrict__ Vb, const int* __restrict__ pad32,
    __bf16* __restrict__ AO) {
  const int n = blockIdx.y;
  const int wave = threadIdx.x >> 6;
  const int lane = threadIdx.x & 63;
  const int g = lane >> 4, c = lane & 15;

  // pad_amounts may be stored as int64 (jax) or int32; detect via high words.
  int thresh = Tn;
  if (n < Bn) {
    bool is64 = (pad32[1] == 0 && pad32[3] == 0);
    int pv = is64 ? pad32[2 * n] : pad32[n];
    thresh = Tn - pv;
  }

  const int q0 = blockIdx.x * 64 + wave * 16;
  const __bf16* Qh = Qb + (long)n * Tn * 64;
  const __bf16* Kh = Kb + (long)n * Tn * 64;
  const __bf16* Vh = Vb + (long)n * Tn * 64;

  bf16x8 aq[2];
  aq[0] = *(const bf16x8*)(Qh + (q0 + c) * 64 + g * 8);
  aq[1] = *(const bf16x8*)(Qh + (q0 + c) * 64 + 32 + g * 8);

  f32x4 oacc[4];
#pragma unroll
  for (int st = 0; st < 4; ++st) oacc[st] = (f32x4){0.f, 0.f, 0.f, 0.f};
  float m[4], lsum[4];
#pragma unroll
  for (int r = 0; r < 4; ++r) { m[r] = NEG_INF; lsum[r] = 0.f; }

  __shared__ __align__(16) __bf16 plds[4][16][40];  // per-wave P tile, padded
  __bf16* pw = &plds[wave][0][0];

  for (int kb = 0; kb < Tn; kb += 32) {
    bf16x8 bk00 = *(const bf16x8*)(Kh + (kb + c) * 64 + g * 8);
    bf16x8 bk01 = *(const bf16x8*)(Kh + (kb + c) * 64 + 32 + g * 8);
    bf16x8 bk10 = *(const bf16x8*)(Kh + (kb + 16 + c) * 64 + g * 8);
    bf16x8 bk11 = *(const bf16x8*)(Kh + (kb + 16 + c) * 64 + 32 + g * 8);

    f32x4 s0 = {0.f, 0.f, 0.f, 0.f}, s1 = {0.f, 0.f, 0.f, 0.f};
    s0 = MFMA16(aq[0], bk00, s0);
    s0 = MFMA16(aq[1], bk01, s0);
    s1 = MFMA16(aq[0], bk10, s1);
    s1 = MFMA16(aq[1], bk11, s1);

    if (kb + 32 > thresh) {  // some column in this tile is >= thresh
#pragma unroll
      for (int r = 0; r < 4; ++r) {
        int q = q0 + g * 4 + r;
        if (q >= thresh) {
          if (kb + c >= thresh) s0[r] = NEG_INF;
          if (kb + 16 + c >= thresh) s1[r] = NEG_INF;
        }
      }
    }

    float mx[4], al[4], p0[4], p1[4], rsum[4];
#pragma unroll
    for (int r = 0; r < 4; ++r) mx[r] = fmaxf(s0[r], s1[r]);
#pragma unroll
    for (int d = 1; d < 16; d <<= 1)
#pragma unroll
      for (int r = 0; r < 4; ++r) mx[r] = fmaxf(mx[r], __shfl_xor(mx[r], d, 64));
#pragma unroll
    for (int r = 0; r < 4; ++r) {
      float mn = fmaxf(m[r], mx[r]);
      al[r] = __expf(m[r] - mn);
      p0[r] = __expf(s0[r] - mn);
      p1[r] = __expf(s1[r] - mn);
      rsum[r] = p0[r] + p1[r];
      m[r] = mn;
    }
#pragma unroll
    for (int d = 1; d < 16; d <<= 1)
#pragma unroll
      for (int r = 0; r < 4; ++r) rsum[r] += __shfl_xor(rsum[r], d, 64);
#pragma unroll
    for (int r = 0; r < 4; ++r) lsum[r] = lsum[r] * al[r] + rsum[r];
#pragma unroll
    for (int st = 0; st < 4; ++st)
#pragma unroll
      for (int r = 0; r < 4; ++r) oacc[st][r] *= al[r];

    // P (16q x 32k) -> LDS in A-fragment-consumable layout
#pragma unroll
    for (int r = 0; r < 4; ++r) {
      pw[(g * 4 + r) * 40 + c] = (__bf16)p0[r];
      pw[(g * 4 + r) * 40 + 16 + c] = (__bf16)p1[r];
    }
    asm volatile("s_waitcnt lgkmcnt(0)" ::: "memory");
    bf16x8 ap = *(const bf16x8*)(pw + c * 40 + g * 8);

#pragma unroll
    for (int st = 0; st < 4; ++st) {
      bf16x8 bv;
      const __bf16* vp = Vh + (kb + g * 8) * 64 + st * 16 + c;
#pragma unroll
      for (int e = 0; e < 8; ++e) bv[e] = vp[e * 64];
      oacc[st] = MFMA16(ap, bv, oacc[st]);
    }
  }

  const int bb = n >> 4, hh = n & 15;
  float inv[4];
#pragma unroll
  for (int r = 0; r < 4; ++r) inv[r] = 1.0f / lsum[r];
#pragma unroll
  for (int st = 0; st < 4; ++st)
#pragma unroll
    for (int r = 0; r < 4; ++r) {
      int q = q0 + g * 4 + r;
      AO[((long)(bb * Tn + q)) * EMBn + hh * 64 + st * 16 + c] =
          (__bf16)(oacc[st][r] * inv[r]);
    }
}

// --------------------------------------------------------------- oproj ----
// Y(8192x1024) = AO(8192x1024) @ Wu^T + bu, fp32 out.
__global__ __launch_bounds__(256) void sa_oproj(
    const __bf16* __restrict__ A, const __bf16* __restrict__ WuB,
    const float* __restrict__ bu, float* __restrict__ Y) {
  const int wave = threadIdx.x >> 6;
  const int lane = threadIdx.x & 63;
  const int g = lane >> 4, c = lane & 15;
  const int mbase = blockIdx.y * 128 + wave * 32;
  const int nbase = blockIdx.x * 64;

  f32x4 acc[2][4];
#pragma unroll
  for (int mt = 0; mt < 2; ++mt)
#pragma unroll
    for (int nt = 0; nt < 4; ++nt) acc[mt][nt] = (f32x4){0.f, 0.f, 0.f, 0.f};

  for (int kb = 0; kb < 1024; kb += 32) {
    bf16x8 a0 = *(const bf16x8*)(A + (long)(mbase + c) * 1024 + kb + g * 8);
    bf16x8 a1 = *(const bf16x8*)(A + (long)(mbase + 16 + c) * 1024 + kb + g * 8);
#pragma unroll
    for (int nt = 0; nt < 4; ++nt) {
      bf16x8 b = *(const bf16x8*)(WuB + (long)(nbase + nt * 16 + c) * 1024 + kb + g * 8);
      acc[0][nt] = MFMA16(a0, b, acc[0][nt]);
      acc[1][nt] = MFMA16(a1, b, acc[1][nt]);
    }
  }

#pragma unroll
  for (int nt = 0; nt < 4; ++nt) {
    float bias = bu[nbase + nt * 16 + c];
#pragma unroll
    for (int mt = 0; mt < 2; ++mt)
#pragma unroll
      for (int r = 0; r < 4; ++r)
        Y[(long)(mbase + mt * 16 + g * 4 + r) * 1024 + nbase + nt * 16 + c] =
            acc[mt][nt][r] + bias;
  }
}

// -------------------------------------------------------------- launch ----
extern "C" void kernel_launch(void* const* d_in, const int* in_sizes, int n_in,
                              void* d_out, int out_size, void* d_ws, size_t ws_size,
                              hipStream_t stream) {
  const float* x  = (const float*)d_in[0];
  const float* Wk = (const float*)d_in[1];
  const float* Wq = (const float*)d_in[2];
  const float* Wv = (const float*)d_in[3];
  const float* Wu = (const float*)d_in[4];
  const float* bu = (const float*)d_in[5];
  const int* pad  = (const int*)d_in[6];
  float* Y = (float*)d_out;

  // workspace layout (elements of __bf16); total 69,238,784 bytes
  __bf16* ws  = (__bf16*)d_ws;
  __bf16* w3  = ws;                        // 12288 (pad to 16384)
  __bf16* wub = ws + 16384;                // 1048576
  __bf16* Qb  = ws + 16384 + 1048576;      // 8388608 each
  __bf16* Kb  = Qb + 8388608;
  __bf16* Vb  = Kb + 8388608;
  __bf16* AO  = Vb + 8388608;

  sa_prep<<<4096, 256, 0, stream>>>(Wk, Wq, Wv, Wu, w3, wub);
  sa_qkv<<<2048, 256, 0, stream>>>(x, w3, Qb, Kb, Vb);
  sa_flash<<<dim3(32, 64), 256, 0, stream>>>(Qb, Kb, Vb, pad, AO);
  sa_oproj<<<dim3(16, 64), 256, 0, stream>>>(AO, wub, bu, Y);
}

// Round 2
// 361.332 us; speedup vs baseline: 1.3389x; 1.3389x over previous
//
#include <hip/hip_runtime.h>

// SelfAttentionNarrow: B=4, T=2048, EMB=1024, H=16, S=64.
// r2: flash rewritten on 32x32x16 MFMA with swapped QK^T (S^T = K·Q^T) so
// softmax stats are lane-local; P^T re-fragmented in-register via
// v_cvt_pk_bf16_f32 + v_permlane32_swap_b32; O^T = V^T · P^T keeps the
// online-softmax rescale lane-local; V produced transposed in qkv.
// exp in log2 domain (scale sqrt(log2e/32) folded into Wq,Wk).

typedef float f32x4 __attribute__((ext_vector_type(4)));
typedef float f32x16 __attribute__((ext_vector_type(16)));
typedef __bf16 bf16x8 __attribute__((ext_vector_type(8)));
typedef unsigned u32x4 __attribute__((ext_vector_type(4)));

#define MFMA16(a, b, c) __builtin_amdgcn_mfma_f32_16x16x32_bf16((a), (b), (c), 0, 0, 0)
#define MFMA32(a, b, c) __builtin_amdgcn_mfma_f32_32x32x16_bf16((a), (b), (c), 0, 0, 0)

constexpr int Tn = 2048;
constexpr int Bn = 4;
constexpr int EMBn = 1024;
constexpr float NEG_INF = -3.0e38f;

__device__ __forceinline__ float exp2_hw(float x) {
  float r; asm("v_exp_f32 %0, %1" : "=v"(r) : "v"(x)); return r;
}
__device__ __forceinline__ unsigned cvtpk(float lo, float hi) {
  unsigned r; asm("v_cvt_pk_bf16_f32 %0, %1, %2" : "=v"(r) : "v"(lo), "v"(hi)); return r;
}
__device__ __forceinline__ void permswap(unsigned& a, unsigned& b) {
  asm("v_permlane32_swap_b32 %0, %1" : "+v"(a), "+v"(b));
}

// ---------------------------------------------------------------- prep ----
// w3: [K*rs | Q*rs | V], rs = sqrt(log2(e)/32) so logits come out in log2 units.
__global__ __launch_bounds__(256) void sa_prep(
    const float* __restrict__ Wk, const float* __restrict__ Wq,
    const float* __restrict__ Wv, const float* __restrict__ Wu,
    __bf16* __restrict__ w3, __bf16* __restrict__ wub) {
  int idx = blockIdx.x * 256 + threadIdx.x;
  const float rs = 0.21233046f;  // sqrt(1.4426950408889634 / 32)
  if (idx < 1048576) wub[idx] = (__bf16)Wu[idx];
  if (idx < 4096) {
    w3[idx]        = (__bf16)(Wk[idx] * rs);
    w3[4096 + idx] = (__bf16)(Wq[idx] * rs);
    w3[8192 + idx] = (__bf16)(Wv[idx]);
  }
}

// ----------------------------------------------------------------- qkv ----
// grid (T/64, B*H). Each wave: 16 t rows of one (b,h). Q,K stored [n][t][s];
// V stored transposed [n][s][t] (via swapped-operand MFMA, coalesced stores).
__global__ __launch_bounds__(256) void sa_qkv(
    const float* __restrict__ x, const __bf16* __restrict__ w3,
    __bf16* __restrict__ Qb, __bf16* __restrict__ Kb, __bf16* __restrict__ Vt) {
  const int wave = threadIdx.x >> 6;
  const int lane = threadIdx.x & 63;
  const int g = lane >> 4, c = lane & 15;
  const int n = blockIdx.y, b = n >> 4, h = n & 15;
  const int t0 = blockIdx.x * 64 + wave * 16;

  // x fragments: usable as both A (row=c=t) and B (col=c=t) operands.
  bf16x8 ax[2];
#pragma unroll
  for (int kk = 0; kk < 2; ++kk) {
    const float* xp = x + ((long)((b * Tn + t0 + c) * 16 + h)) * 64 + kk * 32 + g * 8;
    f32x4 u = *(const f32x4*)xp;
    f32x4 v = *(const f32x4*)(xp + 4);
    bf16x8 a;
    a[0] = (__bf16)u[0]; a[1] = (__bf16)u[1]; a[2] = (__bf16)u[2]; a[3] = (__bf16)u[3];
    a[4] = (__bf16)v[0]; a[5] = (__bf16)v[1]; a[6] = (__bf16)v[2]; a[7] = (__bf16)v[3];
    ax[kk] = a;
  }

  // K (w=0) and Q (w=1): D[t][o] = mfma(A=x, B=W)
#pragma unroll
  for (int w = 0; w < 2; ++w) {
    __bf16* dst = w ? Qb : Kb;
#pragma unroll
    for (int ot = 0; ot < 4; ++ot) {
      f32x4 a_ = {0.f, 0.f, 0.f, 0.f};
#pragma unroll
      for (int kk = 0; kk < 2; ++kk) {
        bf16x8 wf = *(const bf16x8*)(w3 + w * 4096 + (ot * 16 + c) * 64 + kk * 32 + g * 8);
        a_ = MFMA16(ax[kk], wf, a_);
      }
#pragma unroll
      for (int r = 0; r < 4; ++r)
        dst[((long)n * Tn + t0 + g * 4 + r) * 64 + ot * 16 + c] = (__bf16)a_[r];
    }
  }

  // V^T: D[o][t] = mfma(A=Wv, B=x); lanes write contiguous t. Vt[n][s][t].
#pragma unroll
  for (int ot = 0; ot < 4; ++ot) {
    f32x4 a_ = {0.f, 0.f, 0.f, 0.f};
#pragma unroll
    for (int kk = 0; kk < 2; ++kk) {
      bf16x8 wf = *(const bf16x8*)(w3 + 8192 + (ot * 16 + c) * 64 + kk * 32 + g * 8);
      a_ = MFMA16(wf, ax[kk], a_);
    }
#pragma unroll
    for (int r = 0; r < 4; ++r)
      Vt[((long)n * 64 + ot * 16 + g * 4 + r) * Tn + t0 + c] = (__bf16)a_[r];
  }
}

// --------------------------------------------------------------- flash ----
// grid (T/128, B*H), 4 waves/block, each wave owns 32 q rows, KV tile = 32.
// S^T = mfma(K, Q): lane = q = lane&31; reg r = k-row (r&3)+8*(r>>2)+4*hi.
// O^T = mfma(V^T, P^T): lane = q again -> m, l, rescale all lane-local.
__global__ __launch_bounds__(256, 4) void sa_flash(
    const __bf16* __restrict__ Qb, const __bf16* __restrict__ Kb,
    const __bf16* __restrict__ Vt, const int* __restrict__ pad32,
    __bf16* __restrict__ AO) {
  const int n = blockIdx.y;
  const int wave = threadIdx.x >> 6;
  const int lane = threadIdx.x & 63;
  const int ql = lane & 31;
  const int hi = lane >> 5;

  int thresh = Tn;
  if (n < Bn) {
    bool is64 = (pad32[1] == 0 && pad32[3] == 0);
    int pv = is64 ? pad32[2 * n] : pad32[n];
    thresh = Tn - pv;
  }

  const int qbase = blockIdx.x * 128 + wave * 32;
  const __bf16* Qh = Qb + (long)n * Tn * 64;
  const __bf16* Kh = Kb + (long)n * Tn * 64;
  const __bf16* Vh = Vt + (long)n * 64 * Tn;

  // Q fragments (B-operand): col=q=ql, k=s=ks*16+hi*8+e
  bf16x8 bq[4];
  const __bf16* qp = Qh + (long)(qbase + ql) * 64 + hi * 8;
#pragma unroll
  for (int ks = 0; ks < 4; ++ks) bq[ks] = *(const bf16x8*)(qp + ks * 16);

  f32x16 o[2];
#pragma unroll
  for (int i = 0; i < 16; ++i) { o[0][i] = 0.f; o[1][i] = 0.f; }
  float m = NEG_INF, l = 0.f;
  const bool qge = (qbase + ql) >= thresh;
  const bool qany = (qbase + 32) > thresh;

  for (int kb = 0; kb < Tn; kb += 32) {
    // K fragments (A-operand): row=k=ql, k-dim=s
    const __bf16* kp = Kh + (long)(kb + ql) * 64 + hi * 8;
    bf16x8 ka0 = *(const bf16x8*)(kp);
    bf16x8 ka1 = *(const bf16x8*)(kp + 16);
    bf16x8 ka2 = *(const bf16x8*)(kp + 32);
    bf16x8 ka3 = *(const bf16x8*)(kp + 48);

    f32x16 st;
#pragma unroll
    for (int i = 0; i < 16; ++i) st[i] = 0.f;
    st = MFMA32(ka0, bq[0], st);
    st = MFMA32(ka1, bq[1], st);
    st = MFMA32(ka2, bq[2], st);
    st = MFMA32(ka3, bq[3], st);

    if (qany && (kb + 32) > thresh) {
      if (qge) {
#pragma unroll
        for (int r = 0; r < 16; ++r) {
          int kr = kb + (r & 3) + 8 * (r >> 2) + 4 * hi;
          if (kr >= thresh) st[r] = NEG_INF;
        }
      }
    }

    // lane-local max over 16 regs (tree), then cross-half combine
    float t8[8], t4[4], t2[2];
#pragma unroll
    for (int i = 0; i < 8; ++i) t8[i] = fmaxf(st[i], st[i + 8]);
#pragma unroll
    for (int i = 0; i < 4; ++i) t4[i] = fmaxf(t8[i], t8[i + 4]);
    t2[0] = fmaxf(t4[0], t4[2]); t2[1] = fmaxf(t4[1], t4[3]);
    float mloc = fmaxf(t2[0], t2[1]);
    float mtile = fmaxf(mloc, __shfl_xor(mloc, 32, 64));

    if (__any(mtile > m + 8.0f)) {  // defer-max: rescale only on real growth
      float mnew = fmaxf(m, mtile);
      float al = exp2_hw(m - mnew);
      l *= al;
#pragma unroll
      for (int i = 0; i < 16; ++i) { o[0][i] *= al; o[1][i] *= al; }
      m = mnew;
    }

    float p[16];
#pragma unroll
    for (int r = 0; r < 16; ++r) p[r] = exp2_hw(st[r] - m);
    float s8[8], s4[4];
#pragma unroll
    for (int i = 0; i < 8; ++i) s8[i] = p[i] + p[i + 8];
#pragma unroll
    for (int i = 0; i < 4; ++i) s4[i] = s8[i] + s8[i + 4];
    l += (s4[0] + s4[1]) + (s4[2] + s4[3]);  // own half's k only; combined at end

    // P^T -> B-fragments via cvt_pk + permlane32_swap
    unsigned pw[8];
#pragma unroll
    for (int j = 0; j < 2; ++j) {
      unsigned a0 = cvtpk(p[j * 8 + 0], p[j * 8 + 1]);
      unsigned b0 = cvtpk(p[j * 8 + 4], p[j * 8 + 5]);
      permswap(a0, b0);
      unsigned a1 = cvtpk(p[j * 8 + 2], p[j * 8 + 3]);
      unsigned b1 = cvtpk(p[j * 8 + 6], p[j * 8 + 7]);
      permswap(a1, b1);
      pw[j * 4 + 0] = a0; pw[j * 4 + 1] = a1;
      pw[j * 4 + 2] = b0; pw[j * 4 + 3] = b1;
    }
    u32x4 u0 = {pw[0], pw[1], pw[2], pw[3]};
    u32x4 u1 = {pw[4], pw[5], pw[6], pw[7]};
    bf16x8 pb0 = __builtin_bit_cast(bf16x8, u0);
    bf16x8 pb1 = __builtin_bit_cast(bf16x8, u1);

    // V^T fragments (A-operand): row=s=stile*32+ql, k-dim=k (contiguous in t)
    const __bf16* vp = Vh + (long)ql * Tn + kb + hi * 8;
    bf16x8 v00 = *(const bf16x8*)(vp);
    bf16x8 v01 = *(const bf16x8*)(vp + 16);
    bf16x8 v10 = *(const bf16x8*)(vp + 32 * Tn);
    bf16x8 v11 = *(const bf16x8*)(vp + 32 * Tn + 16);

    o[0] = MFMA32(v00, pb0, o[0]);
    o[0] = MFMA32(v01, pb1, o[0]);
    o[1] = MFMA32(v10, pb0, o[1]);
    o[1] = MFMA32(v11, pb1, o[1]);
  }

  float lf = l + __shfl_xor(l, 32, 64);
  float linv = 1.0f / lf;

  // O^T -> LDS (XOR-swizzled) -> coalesced AO stores. Per-wave region, no barrier.
  __shared__ __bf16 tl[4][2048];
  __bf16* my = &tl[wave][0];
#pragma unroll
  for (int stile = 0; stile < 2; ++stile) {
#pragma unroll
    for (int r = 0; r < 16; r += 2) {
      unsigned wv = cvtpk(o[stile][r] * linv, o[stile][r + 1] * linv);
      int s = stile * 32 + (r & 3) + 8 * (r >> 2) + 4 * hi;
      *(unsigned*)(my + ql * 64 + (s ^ ((ql & 7) << 3))) = wv;
    }
  }
  asm volatile("s_waitcnt lgkmcnt(0)" ::: "memory");

  const int bb = n >> 4, hh = n & 15;
  const int qr = lane >> 3, s0 = (lane & 7) * 8;
#pragma unroll
  for (int j = 0; j < 4; ++j) {
    int q = j * 8 + qr;
    bf16x8 vv = *(const bf16x8*)(my + q * 64 + (s0 ^ ((q & 7) << 3)));
    *(bf16x8*)(AO + ((long)(bb * Tn + qbase + q)) * EMBn + hh * 64 + s0) = vv;
  }
}

// --------------------------------------------------------------- oproj ----
__global__ __launch_bounds__(256) void sa_oproj(
    const __bf16* __restrict__ A, const __bf16* __restrict__ WuB,
    const float* __restrict__ bu, float* __restrict__ Y) {
  const int wave = threadIdx.x >> 6;
  const int lane = threadIdx.x & 63;
  const int g = lane >> 4, c = lane & 15;
  const int mbase = blockIdx.y * 128 + wave * 32;
  const int nbase = blockIdx.x * 64;

  f32x4 acc[2][4];
#pragma unroll
  for (int mt = 0; mt < 2; ++mt)
#pragma unroll
    for (int nt = 0; nt < 4; ++nt) acc[mt][nt] = (f32x4){0.f, 0.f, 0.f, 0.f};

  for (int kb = 0; kb < 1024; kb += 32) {
    bf16x8 a0 = *(const bf16x8*)(A + (long)(mbase + c) * 1024 + kb + g * 8);
    bf16x8 a1 = *(const bf16x8*)(A + (long)(mbase + 16 + c) * 1024 + kb + g * 8);
#pragma unroll
    for (int nt = 0; nt < 4; ++nt) {
      bf16x8 b = *(const bf16x8*)(WuB + (long)(nbase + nt * 16 + c) * 1024 + kb + g * 8);
      acc[0][nt] = MFMA16(a0, b, acc[0][nt]);
      acc[1][nt] = MFMA16(a1, b, acc[1][nt]);
    }
  }

#pragma unroll
  for (int nt = 0; nt < 4; ++nt) {
    float bias = bu[nbase + nt * 16 + c];
#pragma unroll
    for (int mt = 0; mt < 2; ++mt)
#pragma unroll
      for (int r = 0; r < 4; ++r)
        Y[(long)(mbase + mt * 16 + g * 4 + r) * 1024 + nbase + nt * 16 + c] =
            acc[mt][nt][r] + bias;
  }
}

// -------------------------------------------------------------- launch ----
extern "C" void kernel_launch(void* const* d_in, const int* in_sizes, int n_in,
                              void* d_out, int out_size, void* d_ws, size_t ws_size,
                              hipStream_t stream) {
  const float* x  = (const float*)d_in[0];
  const float* Wk = (const float*)d_in[1];
  const float* Wq = (const float*)d_in[2];
  const float* Wv = (const float*)d_in[3];
  const float* Wu = (const float*)d_in[4];
  const float* bu = (const float*)d_in[5];
  const int* pad  = (const int*)d_in[6];
  float* Y = (float*)d_out;

  __bf16* ws  = (__bf16*)d_ws;
  __bf16* w3  = ws;                        // 12288 (pad to 16384)
  __bf16* wub = ws + 16384;                // 1048576
  __bf16* Qb  = ws + 16384 + 1048576;      // 8388608 each
  __bf16* Kb  = Qb + 8388608;
  __bf16* Vt  = Kb + 8388608;              // V transposed: [n][s][t]
  __bf16* AO  = Vt + 8388608;

  sa_prep<<<4096, 256, 0, stream>>>(Wk, Wq, Wv, Wu, w3, wub);
  sa_qkv<<<dim3(32, 64), 256, 0, stream>>>(x, w3, Qb, Kb, Vt);
  sa_flash<<<dim3(16, 64), 256, 0, stream>>>(Qb, Kb, Vt, pad, AO);
  sa_oproj<<<dim3(16, 64), 256, 0, stream>>>(AO, wub, bu, Y);
}